// Round 1
// 1898.155 us; speedup vs baseline: 1.0446x; 1.0446x over previous
//
#include <hip/hip_runtime.h>
#include <hip/hip_bf16.h>
#include <math.h>

// ---- problem constants ----
constexpr int Bsz = 32, Cch = 3, IMGS = 224, PP = 16;
constexpr int E = 768, HEADS = 8, Lnum = 6, NC = 1000;
constexpr int HD = 96;
constexpr int NP = 196;
constexpr int Nn = 197;
constexpr int FF = 3072;
constexpr float SCALE = 0.10206207261596575f;  // 96^-0.5
constexpr float EPSc  = 1e-5f;

using short8 = __attribute__((ext_vector_type(8))) short;
using f32x4  = __attribute__((ext_vector_type(4))) float;

__device__ __forceinline__ void async_cp16(const void* g, void* l) {
    __builtin_amdgcn_global_load_lds((const __attribute__((address_space(1))) void*)g,
                                     (__attribute__((address_space(3))) void*)l, 16, 0, 0);
}

// =====================================================================
// f32 -> bf16 convert (single tensor)
// =====================================================================
__global__ void f2b_k(const float* __restrict__ in, __hip_bfloat16* __restrict__ out, int n4) {
    int i = blockIdx.x * 256 + threadIdx.x;
    if (i >= n4) return;
    const float4 v = ((const float4*)in)[i];
    size_t o = (size_t)i * 4;
    out[o + 0] = __float2bfloat16(v.x);
    out[o + 1] = __float2bfloat16(v.y);
    out[o + 2] = __float2bfloat16(v.z);
    out[o + 3] = __float2bfloat16(v.w);
}

// =====================================================================
// fused 4-tensor f32 -> bf16 (one dispatch per layer's weights)
// =====================================================================
__global__ void f2b4_k(const float* __restrict__ s0, const float* __restrict__ s1,
                       const float* __restrict__ s2, const float* __restrict__ s3,
                       __hip_bfloat16* __restrict__ d0, __hip_bfloat16* __restrict__ d1,
                       __hip_bfloat16* __restrict__ d2, __hip_bfloat16* __restrict__ d3,
                       int n0, int n1, int n2, int n3) {
    int i = blockIdx.x * 256 + threadIdx.x;
    const float* s; __hip_bfloat16* d; int base;
    if (i < n0)                { s = s0; d = d0; base = 0; }
    else if (i < n0 + n1)      { s = s1; d = d1; base = n0; }
    else if (i < n0 + n1 + n2) { s = s2; d = d2; base = n0 + n1; }
    else if (i < n0 + n1 + n2 + n3) { s = s3; d = d3; base = n0 + n1 + n2; }
    else return;
    int k = i - base;
    const float4 v = ((const float4*)s)[k];
    size_t o = (size_t)k * 4;
    d[o + 0] = __float2bfloat16(v.x);
    d[o + 1] = __float2bfloat16(v.y);
    d[o + 2] = __float2bfloat16(v.z);
    d[o + 3] = __float2bfloat16(v.w);
}

// =====================================================================
// im2col (bf16 out)
// =====================================================================
__global__ void im2col_k(const float* __restrict__ x, __hip_bfloat16* __restrict__ A) {
    int idx = blockIdx.x * 256 + threadIdx.x;
    if (idx >= Bsz * NP * (Cch * PP * PP)) return;
    int col = idx % 768;
    int row = idx / 768;
    int b  = row / NP;
    int p  = row % NP;
    int hh = p / 14, ww = p % 14;
    int c  = col / 256;
    int rem = col % 256;
    int i = rem / 16, j = rem % 16;
    A[idx] = __float2bfloat16(
        x[(((size_t)b * Cch + c) * IMGS + hh * 16 + i) * IMGS + ww * 16 + j]);
}

// =====================================================================
// bf16 MFMA GEMM. TM = 128 (4 waves x 64x64) or 64 (4 waves x 64x32).
// Round 5 changes:
//  - T1: bijective XCD-chunked block swizzle (m204) so each XCD keeps a
//    contiguous A-panel chunk L2-resident across all N-tiles.
//  - T3/T4: double-buffered LDS, prefetch next K-tile before computing the
//    current one, counted s_waitcnt vmcnt(N) (never 0 in steady state),
//    raw s_barrier + sched_barrier(0) fences (no full vmcnt drain/K-step).
//  LDS: TM=128 -> 32 KB, TM=64 -> 24 KB; still 4 blocks/CU.
// =====================================================================
template <int TM, int OUT_BF16, int ACT, int AHEADS>
__global__ __launch_bounds__(256, 4) void gemm_bf16_k(
    const __hip_bfloat16* __restrict__ A, const __hip_bfloat16* __restrict__ W,
    const float* __restrict__ bias, void* __restrict__ outp,
    int M, int N, int K)
{
    constexpr int NA = TM / 64;            // A chunks per thread (2 for 128, 1 for 64)
    constexpr int JN = (TM == 128) ? 4 : 2; // b-frags per wave
    __shared__ char As[2][TM * 64];
    __shared__ char Bs[2][8192];
    const int tid  = threadIdx.x;
    const int lane = tid & 63;
    const int w    = tid >> 6;

    // ---- T1: bijective XCD-chunked swizzle (m204), decoded y-minor ----
    const int GX = (int)gridDim.x, GY = (int)gridDim.y;
    const int nb  = GX * GY;
    const int lin = (int)blockIdx.x + GX * (int)blockIdx.y;
    const int qq  = nb >> 3, rr = nb & 7;
    const int xcd = lin & 7, j8 = lin >> 3;
    const int s   = (xcd < rr ? xcd * (qq + 1) : rr * (qq + 1) + (xcd - rr) * qq) + j8;
    const int bx  = s / GY;
    const int by  = s - bx * GY;
    const int m0 = bx * TM, n0 = by * 128;
    const int wm = (TM == 128) ? (w & 1) * 64 : 0;
    const int wn = (TM == 128) ? (w >> 1) * 64 : w * 32;

    // ---- A staging pointers (chunk q -> row q>>2, swizzled chunk) ----
    const __hip_bfloat16* agv[NA];
    int abv[NA], acv[NA];
#pragma unroll
    for (int i = 0; i < NA; i++) {
        int q = tid + i * 256;
        int r = q >> 2;
        int c = (q & 3) ^ ((r >> 1) & 3);
        int am = m0 + r; if (am > M - 1) am = M - 1;
        if (AHEADS == 0) {
            agv[i] = A + (size_t)am * K + c * 8;
            abv[i] = 0; acv[i] = 0;
        } else {
            int b_ = am / 197, i_ = am - b_ * 197;
            abv[i] = b_ * 8 * 18912 + i_ * 96;
            acv[i] = c;
            agv[i] = A;
        }
    }
    // ---- B staging pointers (128 rows always) ----
    const int q0 = tid, q1 = tid + 256;
    const int rb0 = q0 >> 2, rb1 = q1 >> 2;
    const int cb0 = (q0 & 3) ^ ((rb0 >> 1) & 3);
    const int cb1 = (q1 & 3) ^ ((rb1 >> 1) & 3);
    const __hip_bfloat16* bg0 = W + (size_t)(n0 + rb0) * K + cb0 * 8;
    const __hip_bfloat16* bg1 = W + (size_t)(n0 + rb1) * K + cb1 * 8;
    char* const asd0 = As[0] + w * 1024;   // wave-uniform LDS dest bases
    char* const asd1 = As[1] + w * 1024;
    char* const bsd0 = Bs[0] + w * 1024;
    char* const bsd1 = Bs[1] + w * 1024;

    // ---- fragment read bases ----
    const int frow = lane & 15, fquad = lane >> 4;
    const int swz = (fquad ^ ((frow >> 1) & 3)) * 16;
    const char* const ar0 = As[0] + (wm + frow) * 64 + swz;
    const char* const ar1 = As[1] + (wm + frow) * 64 + swz;
    const char* const br0 = Bs[0] + (wn + frow) * 64 + swz;
    const char* const br1 = Bs[1] + (wn + frow) * 64 + swz;

    f32x4 acc[4][JN] = {};

#define STAGE(k0_, asd_, bsd_)                                                \
    {                                                                         \
        _Pragma("unroll")                                                     \
        for (int i_ = 0; i_ < NA; i_++) {                                     \
            if (AHEADS == 0) {                                                \
                async_cp16(agv[i_] + (k0_), (asd_) + i_ * 4096);              \
            } else {                                                          \
                int kc_ = acv[i_] + ((k0_) >> 3);                             \
                int h_ = kc_ / 12, dd_ = kc_ - h_ * 12;                       \
                async_cp16(agv[i_] + abv[i_] + h_ * 18912 + dd_ * 8,          \
                           (asd_) + i_ * 4096);                               \
            }                                                                 \
        }                                                                     \
        async_cp16(bg0 + (k0_), (bsd_));                                      \
        async_cp16(bg1 + (k0_), (bsd_) + 4096);                               \
    }

#define WAIT_N()                                                              \
    {                                                                         \
        if constexpr (TM == 128) asm volatile("s_waitcnt vmcnt(4)" ::: "memory"); \
        else                     asm volatile("s_waitcnt vmcnt(3)" ::: "memory"); \
    }

#define FENCE_BAR()                                                           \
    {                                                                         \
        __builtin_amdgcn_sched_barrier(0);                                    \
        __builtin_amdgcn_s_barrier();                                         \
        __builtin_amdgcn_sched_barrier(0);                                    \
    }

#define COMPUTE(arp_, brp_)                                                   \
    {                                                                         \
        short8 af[4], bf[JN];                                                 \
        _Pragma("unroll")                                                     \
        for (int i_ = 0; i_ < 4; i_++) af[i_] = *(const short8*)((arp_) + i_ * 1024); \
        _Pragma("unroll")                                                     \
        for (int j_ = 0; j_ < JN; j_++) bf[j_] = *(const short8*)((brp_) + j_ * 1024); \
        _Pragma("unroll")                                                     \
        for (int i_ = 0; i_ < 4; i_++)                                        \
            _Pragma("unroll")                                                 \
            for (int j_ = 0; j_ < JN; j_++)                                   \
                acc[i_][j_] = __builtin_amdgcn_mfma_f32_16x16x32_bf16(af[i_], bf[j_], acc[i_][j_], 0, 0, 0); \
    }

    const int kiters = K / 32;   // always even (K in {768, 3072})
    STAGE(0, asd0, bsd0);
#pragma unroll 1
    for (int it = 0; it < kiters; it += 2) {
        // --- even step: prefetch buf1 (k=it+1), compute buf0 (k=it) ---
        STAGE((it + 1) * 32, asd1, bsd1);
        WAIT_N();                 // buf0 loads done (all but newest N in flight)
        FENCE_BAR();              // all waves' buf0 staging visible
        COMPUTE(ar0, br0);
        FENCE_BAR();              // buf0 reads done before it's overwritten
        // --- odd step: prefetch buf0 (k=it+2), compute buf1 (k=it+1) ---
        if (it + 2 < kiters) {
            STAGE((it + 2) * 32, asd0, bsd0);
            WAIT_N();
        } else {
            asm volatile("s_waitcnt vmcnt(0)" ::: "memory");
        }
        FENCE_BAR();
        COMPUTE(ar1, br1);
        if (it + 2 < kiters) FENCE_BAR();   // buf1 reads done before overwrite
    }
#undef STAGE
#undef WAIT_N
#undef FENCE_BAR
#undef COMPUTE

    // ---- epilogue (C/D layout: col=lane&15, row=(lane>>4)*4+reg) ----
#pragma unroll
    for (int i = 0; i < 4; i++) {
#pragma unroll
        for (int j = 0; j < JN; j++) {
#pragma unroll
            for (int r = 0; r < 4; r++) {
                int row = m0 + wm + i * 16 + fquad * 4 + r;
                int col = n0 + wn + j * 16 + frow;
                if (row < M) {
                    float v = acc[i][j][r] + bias[col];
                    if (ACT == 1) v = 0.5f * v * (1.0f + erff(v * 0.70710678118654752f));
                    if (OUT_BF16) ((__hip_bfloat16*)outp)[(size_t)row * N + col] = __float2bfloat16(v);
                    else          ((float*)outp)[(size_t)row * N + col] = v;
                }
            }
        }
    }
}

// =====================================================================
// assemble
// =====================================================================
__global__ void assemble_k(const float* __restrict__ ptmp, const float* __restrict__ cls,
                           const float* __restrict__ pos, float* __restrict__ X,
                           __hip_bfloat16* __restrict__ Xb) {
    int idx = blockIdx.x * 256 + threadIdx.x;
    if (idx >= Bsz * Nn * E) return;
    int e = idx % E;
    int r = idx / E;
    int n = r % Nn, b = r / Nn;
    float v = (n == 0) ? cls[e] : ptmp[((size_t)b * NP + (n - 1)) * E + e];
    v += pos[(size_t)n * E + e];
    X[idx] = v;
    Xb[idx] = __float2bfloat16(v);
}

// =====================================================================
// V transpose: Vtg[bh][d][j] (row stride 232 shorts), padded cols zeroed
// =====================================================================
__global__ void vtr_k(const __hip_bfloat16* __restrict__ qkv, __hip_bfloat16* __restrict__ Vtg) {
    __shared__ short T[64][104];
    const int tid = threadIdx.x;
    const int bh = blockIdx.y, jc = blockIdx.x;
    const int b = bh >> 3, h = bh & 7;
    const int j0 = jc * 64;
#pragma unroll
    for (int it = 0; it < 3; it++) {
        int idx = it * 256 + tid;
        int jl = idx / 12, off = (idx % 12) * 8;
        int j = j0 + jl;
        short8 v = {0, 0, 0, 0, 0, 0, 0, 0};
        if (j <= 196)
            v = *(const short8*)(qkv + (size_t)(b * Nn + j) * 2304 + 1536 + h * 96 + off);
        *(short8*)(&T[jl][off]) = v;
    }
    __syncthreads();
#pragma unroll
    for (int it = 0; it < 3; it++) {
        int idx = it * 256 + tid;
        int d = idx >> 3, c = idx & 7;
        int col = j0 + c * 8;
        if (col < 232) {
            short8 v;
#pragma unroll
            for (int k = 0; k < 8; k++) v[k] = T[c * 8 + k][d];
            *(short8*)(Vtg + ((size_t)bh * 96 + d) * 232 + col) = v;
        }
    }
}

// =====================================================================
// Fused attention, one block per (b,h) — unchanged.
// =====================================================================
__global__ __launch_bounds__(256, 1) void fattn_k(
    const __hip_bfloat16* __restrict__ qkv,
    const __hip_bfloat16* __restrict__ Vtg,
    __hip_bfloat16* __restrict__ atth)
{
    __shared__ __align__(16) char SL[44544 + 4 * 1280];
    char* const Ps = SL + 44544;
    const int tid = threadIdx.x, lane = tid & 63, w = tid >> 6;
    const int bh = blockIdx.x;
    const int b = bh >> 3, h = bh & 7;
    const int frow = lane & 15, quad = lane >> 4;

#pragma unroll
    for (int it = 0; it < 10; it++) {
        int c = it * 256 + tid;
        if (c < 197 * 12) {
            int j = c / 12, cc = c % 12;
            short8 v = *(const short8*)(qkv + ((size_t)(b * 197 + j)) * 2304 + 768 + h * 96 + cc * 8);
            *(short8*)(SL + j * 208 + cc * 16) = v;
        }
    }
    __syncthreads();

    short8 pf[4][7];
#pragma unroll 1
    for (int t = 0; t < 4; t++) {
        const int mt = w + 4 * t;
        if (mt >= 13) break;
        const int qi = min(mt * 16 + frow, 196);
        const __hip_bfloat16* qrow = qkv + ((size_t)(b * 197 + qi)) * 2304 + h * 96 + quad * 8;
        short8 qf[3];
#pragma unroll
        for (int kc = 0; kc < 3; kc++) qf[kc] = *(const short8*)(qrow + kc * 32);

        f32x4 sacc[13];
#pragma unroll
        for (int nt = 0; nt < 13; nt++) sacc[nt] = (f32x4){0.f, 0.f, 0.f, 0.f};
#pragma unroll
        for (int nt = 0; nt < 13; nt++) {
#pragma unroll
            for (int kc = 0; kc < 3; kc++) {
                short8 kf = *(const short8*)(SL + (nt * 16 + frow) * 208 + (kc * 32 + quad * 8) * 2);
                sacc[nt] = __builtin_amdgcn_mfma_f32_16x16x32_bf16(qf[kc], kf, sacc[nt], 0, 0, 0);
            }
        }

        float mx[4] = {-1e30f, -1e30f, -1e30f, -1e30f};
#pragma unroll
        for (int nt = 0; nt < 13; nt++) {
            bool masked = (nt == 12) && (frow >= 5);
#pragma unroll
            for (int r = 0; r < 4; r++) {
                float v = masked ? -1e30f : sacc[nt][r];
                sacc[nt][r] = v;
                mx[r] = fmaxf(mx[r], v);
            }
        }
#pragma unroll
        for (int m = 1; m <= 8; m <<= 1)
#pragma unroll
            for (int r = 0; r < 4; r++) mx[r] = fmaxf(mx[r], __shfl_xor(mx[r], m));
        float sm[4] = {0.f, 0.f, 0.f, 0.f};
#pragma unroll
        for (int nt = 0; nt < 13; nt++) {
            bool masked = (nt == 12) && (frow >= 5);
#pragma unroll
            for (int r = 0; r < 4; r++) {
                float e = masked ? 0.f : __expf(sacc[nt][r] - mx[r]);
                sacc[nt][r] = e;
                sm[r] += e;
            }
        }
#pragma unroll
        for (int m = 1; m <= 8; m <<= 1)
#pragma unroll
            for (int r = 0; r < 4; r++) sm[r] += __shfl_xor(sm[r], m);
        float inv[4];
#pragma unroll
        for (int r = 0; r < 4; r++) inv[r] = SCALE / sm[r];

        char* const myPs = Ps + w * 1280;
#pragma unroll
        for (int kc = 0; kc < 7; kc++) {
#pragma unroll
            for (int tt = 0; tt < 2; tt++) {
                int t2 = kc * 2 + tt;
#pragma unroll
                for (int r = 0; r < 4; r++) {
                    float pv = (t2 < 13) ? sacc[t2][r] * inv[r] : 0.f;
                    *(__hip_bfloat16*)(myPs + (quad * 4 + r) * 80 + (tt * 16 + frow) * 2) =
                        __float2bfloat16(pv);
                }
            }
            pf[t][kc] = *(const short8*)(myPs + frow * 80 + quad * 16);
        }
    }
    __syncthreads();

    {
        const char* src = (const char*)(Vtg + (size_t)bh * 96 * 232);
#pragma unroll
        for (int i = 0; i < 11; i++) {
            int c = i * 256 + w * 64 + lane;
            if (c < 96 * 29)
                async_cp16(src + (size_t)c * 16, SL + (size_t)(i * 256 + w * 64) * 16);
        }
    }
    __syncthreads();

#pragma unroll 1
    for (int t = 0; t < 4; t++) {
        const int mt = w + 4 * t;
        if (mt >= 13) break;
        f32x4 oacc[6];
#pragma unroll
        for (int dt = 0; dt < 6; dt++) oacc[dt] = (f32x4){0.f, 0.f, 0.f, 0.f};
#pragma unroll
        for (int kc = 0; kc < 7; kc++) {
#pragma unroll
            for (int dt = 0; dt < 6; dt++) {
                short8 vf = *(const short8*)(SL + (size_t)(dt * 16 + frow) * 464 +
                                             (kc * 32 + quad * 8) * 2);
                oacc[dt] = __builtin_amdgcn_mfma_f32_16x16x32_bf16(pf[t][kc], vf, oacc[dt], 0, 0, 0);
            }
        }
#pragma unroll
        for (int dt = 0; dt < 6; dt++)
#pragma unroll
            for (int r = 0; r < 4; r++) {
                int i = mt * 16 + quad * 4 + r;
                if (i < 197)
                    atth[((size_t)bh * 197 + i) * 96 + dt * 16 + frow] =
                        __float2bfloat16(oacc[dt][r]);
            }
    }
}

// =====================================================================
// x = LN(x + t); writes f32 X in place and bf16 shadow Xb
// =====================================================================
__global__ void add_ln_k(float* __restrict__ X, const float* __restrict__ T,
                         const float* __restrict__ g, const float* __restrict__ bb,
                         __hip_bfloat16* __restrict__ Xb) {
    const size_t row = blockIdx.x;
    float* xr = X + row * E;
    const float* tr = T + row * E;
    const int t = threadIdx.x;
    __shared__ float red[4];
    float v[3];
    float s = 0.f;
#pragma unroll
    for (int i = 0; i < 3; i++) {
        v[i] = xr[t + i * 256] + tr[t + i * 256];
        s += v[i];
    }
    for (int off = 32; off > 0; off >>= 1) s += __shfl_down(s, off);
    int wid = t >> 6, lane = t & 63;
    if (lane == 0) red[wid] = s;
    __syncthreads();
    if (t == 0) red[0] = red[0] + red[1] + red[2] + red[3];
    __syncthreads();
    float mean = red[0] / 768.f;
    __syncthreads();
    float s2 = 0.f;
#pragma unroll
    for (int i = 0; i < 3; i++) {
        float dl = v[i] - mean;
        s2 += dl * dl;
    }
    for (int off = 32; off > 0; off >>= 1) s2 += __shfl_down(s2, off);
    if (lane == 0) red[wid] = s2;
    __syncthreads();
    if (t == 0) red[0] = red[0] + red[1] + red[2] + red[3];
    __syncthreads();
    float rs = rsqrtf(red[0] / 768.f + EPSc);
#pragma unroll
    for (int i = 0; i < 3; i++) {
        int e = t + i * 256;
        float o = (v[i] - mean) * rs * g[e] + bb[e];
        xr[e] = o;
        Xb[row * E + e] = __float2bfloat16(o);
    }
}

// =====================================================================
// mean pool over N + LN -> pooled
// =====================================================================
__global__ void pool_ln_k(const float* __restrict__ X, const float* __restrict__ g,
                          const float* __restrict__ bb, float* __restrict__ pooled) {
    __shared__ float red[4];
    const int b = blockIdx.x, t = threadIdx.x;
    float loc[3];
#pragma unroll
    for (int i = 0; i < 3; i++) {
        int e = t + i * 256;
        float s = 0.f;
        for (int n = 0; n < Nn; n++) s += X[((size_t)(b * Nn + n)) * E + e];
        loc[i] = s / (float)Nn;
    }
    float s = loc[0] + loc[1] + loc[2];
    for (int off = 32; off > 0; off >>= 1) s += __shfl_down(s, off);
    int wid = t >> 6, lane = t & 63;
    if (lane == 0) red[wid] = s;
    __syncthreads();
    if (t == 0) red[0] = red[0] + red[1] + red[2] + red[3];
    __syncthreads();
    float mean = red[0] / 768.f;
    __syncthreads();
    float s2 = 0.f;
#pragma unroll
    for (int i = 0; i < 3; i++) {
        float dl = loc[i] - mean;
        s2 += dl * dl;
    }
    for (int off = 32; off > 0; off >>= 1) s2 += __shfl_down(s2, off);
    if (lane == 0) red[wid] = s2;
    __syncthreads();
    if (t == 0) red[0] = red[0] + red[1] + red[2] + red[3];
    __syncthreads();
    float rs = rsqrtf(red[0] / 768.f + EPSc);
#pragma unroll
    for (int i = 0; i < 3; i++) {
        int e = t + i * 256;
        pooled[(size_t)b * E + e] = (loc[i] - mean) * rs * g[e] + bb[e];
    }
}

// =====================================================================
// head matvec
// =====================================================================
__global__ void head_k(const float* __restrict__ pooled, const float* __restrict__ hw,
                       const float* __restrict__ hb, float* __restrict__ out) {
    __shared__ float ps[768];
    const int b = blockIdx.y;
    const int s = blockIdx.x;
    const int t = threadIdx.x, lane = t & 63, w = t >> 6;
    for (int e = t; e < 768; e += 256) ps[e] = pooled[(size_t)b * E + e];
    __syncthreads();
    float pl[12];
#pragma unroll
    for (int j = 0; j < 12; j++) pl[j] = ps[j * 64 + lane];
    for (int i = 0; i < 10; i++) {
        int o = s * 40 + w * 10 + i;
        const float* wr = hw + (size_t)o * 768;
        float acc = 0.f;
#pragma unroll
        for (int j = 0; j < 12; j++) acc += pl[j] * wr[j * 64 + lane];
        for (int off = 32; off > 0; off >>= 1) acc += __shfl_down(acc, off);
        if (lane == 0) out[(size_t)b * NC + o] = acc + hb[o];
    }
}

// =====================================================================
extern "C" void kernel_launch(void* const* d_in, const int* in_sizes, int n_in,
                              void* d_out, int out_size, void* d_ws, size_t ws_size,
                              hipStream_t stream) {
    const float* x        = (const float*)d_in[0];
    const float* conv_w   = (const float*)d_in[1];
    const float* conv_b   = (const float*)d_in[2];
    const float* cls_tok  = (const float*)d_in[3];
    const float* pos_emb  = (const float*)d_in[4];
    const float* qkv_w    = (const float*)d_in[5];
    const float* qkv_b    = (const float*)d_in[6];
    const float* proj_w   = (const float*)d_in[7];
    const float* proj_b   = (const float*)d_in[8];
    const float* ln1_g    = (const float*)d_in[9];
    const float* ln1_b    = (const float*)d_in[10];
    const float* mlp_w1   = (const float*)d_in[11];
    const float* mlp_b1   = (const float*)d_in[12];
    const float* mlp_w2   = (const float*)d_in[13];
    const float* mlp_b2   = (const float*)d_in[14];
    const float* ln2_g    = (const float*)d_in[15];
    const float* ln2_b    = (const float*)d_in[16];
    const float* hln_g    = (const float*)d_in[17];
    const float* hln_b    = (const float*)d_in[18];
    const float* head_w   = (const float*)d_in[19];
    const float* head_b   = (const float*)d_in[20];
    float* out = (float*)d_out;

    const int M = Bsz * Nn;  // 6304

    // ---- workspace carve-up ----
    char* p = (char*)d_ws;
    __hip_bfloat16* Xb   = (__hip_bfloat16*)p;  p += (size_t)M * E * 2;
    float*          X    = (float*)p;           p += (size_t)M * E * 4;
    __hip_bfloat16* qwb  = (__hip_bfloat16*)p;  p += (size_t)3 * E * E * 2;
    __hip_bfloat16* pwb  = (__hip_bfloat16*)p;  p += (size_t)E * E * 2;
    __hip_bfloat16* w1b  = (__hip_bfloat16*)p;  p += (size_t)FF * E * 2;
    __hip_bfloat16* w2b  = (__hip_bfloat16*)p;  p += (size_t)E * FF * 2;
    __hip_bfloat16* cwb  = (__hip_bfloat16*)p;  p += (size_t)E * E * 2;
    __hip_bfloat16* atth = (__hip_bfloat16*)p;  p += (size_t)M * E * 2;  // head-major [bh][197][96]
    float*          pool = (float*)p;           p += (size_t)Bsz * E * 4;
    char* R = p;
    // live set A (attention): qkvb + Vtg ; live set B (patch/MLP): Hb + Ctmp
    __hip_bfloat16* qkvb = (__hip_bfloat16*)R;
    __hip_bfloat16* Vtg  = (__hip_bfloat16*)(R + 29048832);
    __hip_bfloat16* Hb   = (__hip_bfloat16*)R;
    float*          Ctmp = (float*)(R + 40452096);
    __hip_bfloat16* imb  = (__hip_bfloat16*)R;

    // ---- patch embed ----
    {
        f2b_k<<<(E * E / 4 + 255) / 256, 256, 0, stream>>>(conv_w, cwb, E * E / 4);
        int tot = Bsz * NP * 768;
        im2col_k<<<(tot + 255) / 256, 256, 0, stream>>>(x, imb);
        dim3 g(98, 6);  // M=6272 = 98*64
        gemm_bf16_k<64, 0, 0, 0><<<g, 256, 0, stream>>>(imb, cwb, conv_b, Ctmp, Bsz * NP, E, E);
        int tot2 = Bsz * Nn * E;
        assemble_k<<<(tot2 + 255) / 256, 256, 0, stream>>>(Ctmp, cls_tok, pos_emb, X, Xb);
    }

    const int MB128 = (M + 127) / 128;  // 50
    const int MB64  = (M + 63) / 64;    // 99
    const int cn0 = 3 * E * E / 4, cn1 = E * E / 4, cn2 = FF * E / 4, cn3 = E * FF / 4;
    const int cgrid = (cn0 + cn1 + cn2 + cn3 + 255) / 256;

    // ---- transformer layers ----
    for (int l = 0; l < Lnum; l++) {
        const float* qw = qkv_w + (size_t)l * 3 * E * E;
        const float* qb = qkv_b + (size_t)l * 3 * E;
        const float* pw = proj_w + (size_t)l * E * E;
        const float* pb = proj_b + (size_t)l * E;
        const float* g1 = ln1_g + (size_t)l * E;
        const float* b1 = ln1_b + (size_t)l * E;
        const float* w1 = mlp_w1 + (size_t)l * FF * E;
        const float* bb1 = mlp_b1 + (size_t)l * FF;
        const float* w2 = mlp_w2 + (size_t)l * E * FF;
        const float* bb2 = mlp_b2 + (size_t)l * E;
        const float* g2 = ln2_g + (size_t)l * E;
        const float* b2 = ln2_b + (size_t)l * E;

        f2b4_k<<<cgrid, 256, 0, stream>>>(qw, pw, w1, w2, qwb, pwb, w1b, w2b,
                                          cn0, cn1, cn2, cn3);

        // qkv = Xb @ qwb^T -> bf16 [M, 2304]
        gemm_bf16_k<128, 1, 0, 0><<<dim3(MB128, 18), 256, 0, stream>>>(Xb, qwb, qb, qkvb, M, 3 * E, E);
        // V transpose into Vtg
        vtr_k<<<dim3(4, Bsz * HEADS), 256, 0, stream>>>(qkvb, Vtg);
        // fused attention -> atth (head-major)
        fattn_k<<<Bsz * HEADS, 256, 0, stream>>>(qkvb, Vtg, atth);
        // proj (A head-major) -> f32 Ctmp
        gemm_bf16_k<64, 0, 0, 1><<<dim3(MB64, 6), 256, 0, stream>>>(atth, pwb, pb, Ctmp, M, E, E);
        add_ln_k<<<M, 256, 0, stream>>>(X, Ctmp, g1, b1, Xb);
        // MLP1 + gelu -> bf16 Hb
        gemm_bf16_k<128, 1, 1, 0><<<dim3(MB128, 24), 256, 0, stream>>>(Xb, w1b, bb1, Hb, M, FF, E);
        // MLP2 -> f32 Ctmp
        gemm_bf16_k<64, 0, 0, 0><<<dim3(MB64, 6), 256, 0, stream>>>(Hb, w2b, bb2, Ctmp, M, E, FF);
        add_ln_k<<<M, 256, 0, stream>>>(X, Ctmp, g2, b2, Xb);
    }

    // ---- head ----
    pool_ln_k<<<Bsz, 256, 0, stream>>>(X, hln_g, hln_b, pool);
    head_k<<<dim3(25, Bsz), 256, 0, stream>>>(pool, head_w, head_b, out);
}

// Round 2
// 1790.726 us; speedup vs baseline: 1.1072x; 1.0600x over previous
//
#include <hip/hip_runtime.h>
#include <hip/hip_bf16.h>
#include <math.h>

// ---- problem constants ----
constexpr int Bsz = 32, Cch = 3, IMGS = 224, PP = 16;
constexpr int E = 768, HEADS = 8, Lnum = 6, NC = 1000;
constexpr int HD = 96;
constexpr int NP = 196;
constexpr int Nn = 197;
constexpr int FF = 3072;
constexpr float SCALE = 0.10206207261596575f;  // 96^-0.5
constexpr float EPSc  = 1e-5f;

using short8 = __attribute__((ext_vector_type(8))) short;
using f32x4  = __attribute__((ext_vector_type(4))) float;

__device__ __forceinline__ void async_cp16(const void* g, void* l) {
    __builtin_amdgcn_global_load_lds((const __attribute__((address_space(1))) void*)g,
                                     (__attribute__((address_space(3))) void*)l, 16, 0, 0);
}

// =====================================================================
// f32 -> bf16 convert (single tensor)
// =====================================================================
__global__ void f2b_k(const float* __restrict__ in, __hip_bfloat16* __restrict__ out, int n4) {
    int i = blockIdx.x * 256 + threadIdx.x;
    if (i >= n4) return;
    const float4 v = ((const float4*)in)[i];
    size_t o = (size_t)i * 4;
    out[o + 0] = __float2bfloat16(v.x);
    out[o + 1] = __float2bfloat16(v.y);
    out[o + 2] = __float2bfloat16(v.z);
    out[o + 3] = __float2bfloat16(v.w);
}

// =====================================================================
// fused 4-tensor f32 -> bf16 (one dispatch per layer's weights)
// =====================================================================
__global__ void f2b4_k(const float* __restrict__ s0, const float* __restrict__ s1,
                       const float* __restrict__ s2, const float* __restrict__ s3,
                       __hip_bfloat16* __restrict__ d0, __hip_bfloat16* __restrict__ d1,
                       __hip_bfloat16* __restrict__ d2, __hip_bfloat16* __restrict__ d3,
                       int n0, int n1, int n2, int n3) {
    int i = blockIdx.x * 256 + threadIdx.x;
    const float* s; __hip_bfloat16* d; int base;
    if (i < n0)                { s = s0; d = d0; base = 0; }
    else if (i < n0 + n1)      { s = s1; d = d1; base = n0; }
    else if (i < n0 + n1 + n2) { s = s2; d = d2; base = n0 + n1; }
    else if (i < n0 + n1 + n2 + n3) { s = s3; d = d3; base = n0 + n1 + n2; }
    else return;
    int k = i - base;
    const float4 v = ((const float4*)s)[k];
    size_t o = (size_t)k * 4;
    d[o + 0] = __float2bfloat16(v.x);
    d[o + 1] = __float2bfloat16(v.y);
    d[o + 2] = __float2bfloat16(v.z);
    d[o + 3] = __float2bfloat16(v.w);
}

// =====================================================================
// im2col (bf16 out)
// =====================================================================
__global__ void im2col_k(const float* __restrict__ x, __hip_bfloat16* __restrict__ A) {
    int idx = blockIdx.x * 256 + threadIdx.x;
    if (idx >= Bsz * NP * (Cch * PP * PP)) return;
    int col = idx % 768;
    int row = idx / 768;
    int b  = row / NP;
    int p  = row % NP;
    int hh = p / 14, ww = p % 14;
    int c  = col / 256;
    int rem = col % 256;
    int i = rem / 16, j = rem % 16;
    A[idx] = __float2bfloat16(
        x[(((size_t)b * Cch + c) * IMGS + hh * 16 + i) * IMGS + ww * 16 + j]);
}

// =====================================================================
// bf16 MFMA GEMM. TM = 128 (4 waves x 64x64) or 64 (4 waves x 64x32).
//  - T1: bijective XCD-chunked block swizzle (m204).
//  - T3/T4: double-buffered LDS, counted s_waitcnt vmcnt(N).
// =====================================================================
template <int TM, int OUT_BF16, int ACT, int AHEADS>
__global__ __launch_bounds__(256, 4) void gemm_bf16_k(
    const __hip_bfloat16* __restrict__ A, const __hip_bfloat16* __restrict__ W,
    const float* __restrict__ bias, void* __restrict__ outp,
    int M, int N, int K)
{
    constexpr int NA = TM / 64;            // A chunks per thread (2 for 128, 1 for 64)
    constexpr int JN = (TM == 128) ? 4 : 2; // b-frags per wave
    __shared__ char As[2][TM * 64];
    __shared__ char Bs[2][8192];
    const int tid  = threadIdx.x;
    const int lane = tid & 63;
    const int w    = tid >> 6;

    // ---- T1: bijective XCD-chunked swizzle (m204), decoded y-minor ----
    const int GX = (int)gridDim.x, GY = (int)gridDim.y;
    const int nb  = GX * GY;
    const int lin = (int)blockIdx.x + GX * (int)blockIdx.y;
    const int qq  = nb >> 3, rr = nb & 7;
    const int xcd = lin & 7, j8 = lin >> 3;
    const int s   = (xcd < rr ? xcd * (qq + 1) : rr * (qq + 1) + (xcd - rr) * qq) + j8;
    const int bx  = s / GY;
    const int by  = s - bx * GY;
    const int m0 = bx * TM, n0 = by * 128;
    const int wm = (TM == 128) ? (w & 1) * 64 : 0;
    const int wn = (TM == 128) ? (w >> 1) * 64 : w * 32;

    // ---- A staging pointers (chunk q -> row q>>2, swizzled chunk) ----
    const __hip_bfloat16* agv[NA];
    int abv[NA], acv[NA];
#pragma unroll
    for (int i = 0; i < NA; i++) {
        int q = tid + i * 256;
        int r = q >> 2;
        int c = (q & 3) ^ ((r >> 1) & 3);
        int am = m0 + r; if (am > M - 1) am = M - 1;
        if (AHEADS == 0) {
            agv[i] = A + (size_t)am * K + c * 8;
            abv[i] = 0; acv[i] = 0;
        } else {
            int b_ = am / 197, i_ = am - b_ * 197;
            abv[i] = b_ * 8 * 18912 + i_ * 96;
            acv[i] = c;
            agv[i] = A;
        }
    }
    // ---- B staging pointers (128 rows always) ----
    const int q0 = tid, q1 = tid + 256;
    const int rb0 = q0 >> 2, rb1 = q1 >> 2;
    const int cb0 = (q0 & 3) ^ ((rb0 >> 1) & 3);
    const int cb1 = (q1 & 3) ^ ((rb1 >> 1) & 3);
    const __hip_bfloat16* bg0 = W + (size_t)(n0 + rb0) * K + cb0 * 8;
    const __hip_bfloat16* bg1 = W + (size_t)(n0 + rb1) * K + cb1 * 8;
    char* const asd0 = As[0] + w * 1024;   // wave-uniform LDS dest bases
    char* const asd1 = As[1] + w * 1024;
    char* const bsd0 = Bs[0] + w * 1024;
    char* const bsd1 = Bs[1] + w * 1024;

    // ---- fragment read bases ----
    const int frow = lane & 15, fquad = lane >> 4;
    const int swz = (fquad ^ ((frow >> 1) & 3)) * 16;
    const char* const ar0 = As[0] + (wm + frow) * 64 + swz;
    const char* const ar1 = As[1] + (wm + frow) * 64 + swz;
    const char* const br0 = Bs[0] + (wn + frow) * 64 + swz;
    const char* const br1 = Bs[1] + (wn + frow) * 64 + swz;

    f32x4 acc[4][JN] = {};

#define STAGE(k0_, asd_, bsd_)                                                \
    {                                                                         \
        _Pragma("unroll")                                                     \
        for (int i_ = 0; i_ < NA; i_++) {                                     \
            if (AHEADS == 0) {                                                \
                async_cp16(agv[i_] + (k0_), (asd_) + i_ * 4096);              \
            } else {                                                          \
                int kc_ = acv[i_] + ((k0_) >> 3);                             \
                int h_ = kc_ / 12, dd_ = kc_ - h_ * 12;                       \
                async_cp16(agv[i_] + abv[i_] + h_ * 18912 + dd_ * 8,          \
                           (asd_) + i_ * 4096);                               \
            }                                                                 \
        }                                                                     \
        async_cp16(bg0 + (k0_), (bsd_));                                      \
        async_cp16(bg1 + (k0_), (bsd_) + 4096);                               \
    }

#define WAIT_N()                                                              \
    {                                                                         \
        if constexpr (TM == 128) asm volatile("s_waitcnt vmcnt(4)" ::: "memory"); \
        else                     asm volatile("s_waitcnt vmcnt(3)" ::: "memory"); \
    }

#define FENCE_BAR()                                                           \
    {                                                                         \
        __builtin_amdgcn_sched_barrier(0);                                    \
        __builtin_amdgcn_s_barrier();                                         \
        __builtin_amdgcn_sched_barrier(0);                                    \
    }

#define COMPUTE(arp_, brp_)                                                   \
    {                                                                         \
        short8 af[4], bf[JN];                                                 \
        _Pragma("unroll")                                                     \
        for (int i_ = 0; i_ < 4; i_++) af[i_] = *(const short8*)((arp_) + i_ * 1024); \
        _Pragma("unroll")                                                     \
        for (int j_ = 0; j_ < JN; j_++) bf[j_] = *(const short8*)((brp_) + j_ * 1024); \
        _Pragma("unroll")                                                     \
        for (int i_ = 0; i_ < 4; i_++)                                        \
            _Pragma("unroll")                                                 \
            for (int j_ = 0; j_ < JN; j_++)                                   \
                acc[i_][j_] = __builtin_amdgcn_mfma_f32_16x16x32_bf16(af[i_], bf[j_], acc[i_][j_], 0, 0, 0); \
    }

    const int kiters = K / 32;   // always even (K in {768, 3072})
    STAGE(0, asd0, bsd0);
#pragma unroll 1
    for (int it = 0; it < kiters; it += 2) {
        // --- even step: prefetch buf1 (k=it+1), compute buf0 (k=it) ---
        STAGE((it + 1) * 32, asd1, bsd1);
        WAIT_N();                 // buf0 loads done (all but newest N in flight)
        FENCE_BAR();              // all waves' buf0 staging visible
        COMPUTE(ar0, br0);
        FENCE_BAR();              // buf0 reads done before it's overwritten
        // --- odd step: prefetch buf0 (k=it+2), compute buf1 (k=it+1) ---
        if (it + 2 < kiters) {
            STAGE((it + 2) * 32, asd0, bsd0);
            WAIT_N();
        } else {
            asm volatile("s_waitcnt vmcnt(0)" ::: "memory");
        }
        FENCE_BAR();
        COMPUTE(ar1, br1);
        if (it + 2 < kiters) FENCE_BAR();   // buf1 reads done before overwrite
    }
#undef STAGE
#undef WAIT_N
#undef FENCE_BAR
#undef COMPUTE

    // ---- epilogue (C/D layout: col=lane&15, row=(lane>>4)*4+reg) ----
#pragma unroll
    for (int i = 0; i < 4; i++) {
#pragma unroll
        for (int j = 0; j < JN; j++) {
#pragma unroll
            for (int r = 0; r < 4; r++) {
                int row = m0 + wm + i * 16 + fquad * 4 + r;
                int col = n0 + wn + j * 16 + frow;
                if (row < M) {
                    float v = acc[i][j][r] + bias[col];
                    if (ACT == 1) v = 0.5f * v * (1.0f + erff(v * 0.70710678118654752f));
                    if (OUT_BF16) ((__hip_bfloat16*)outp)[(size_t)row * N + col] = __float2bfloat16(v);
                    else          ((float*)outp)[(size_t)row * N + col] = v;
                }
            }
        }
    }
}

// =====================================================================
// assemble
// =====================================================================
__global__ void assemble_k(const float* __restrict__ ptmp, const float* __restrict__ cls,
                           const float* __restrict__ pos, float* __restrict__ X,
                           __hip_bfloat16* __restrict__ Xb) {
    int idx = blockIdx.x * 256 + threadIdx.x;
    if (idx >= Bsz * Nn * E) return;
    int e = idx % E;
    int r = idx / E;
    int n = r % Nn, b = r / Nn;
    float v = (n == 0) ? cls[e] : ptmp[((size_t)b * NP + (n - 1)) * E + e];
    v += pos[(size_t)n * E + e];
    X[idx] = v;
    Xb[idx] = __float2bfloat16(v);
}

// =====================================================================
// V transpose: Vtg[bh][d][j] (row stride 232 shorts), padded cols zeroed
// =====================================================================
__global__ void vtr_k(const __hip_bfloat16* __restrict__ qkv, __hip_bfloat16* __restrict__ Vtg) {
    __shared__ short T[64][104];
    const int tid = threadIdx.x;
    const int bh = blockIdx.y, jc = blockIdx.x;
    const int b = bh >> 3, h = bh & 7;
    const int j0 = jc * 64;
#pragma unroll
    for (int it = 0; it < 3; it++) {
        int idx = it * 256 + tid;
        int jl = idx / 12, off = (idx % 12) * 8;
        int j = j0 + jl;
        short8 v = {0, 0, 0, 0, 0, 0, 0, 0};
        if (j <= 196)
            v = *(const short8*)(qkv + (size_t)(b * Nn + j) * 2304 + 1536 + h * 96 + off);
        *(short8*)(&T[jl][off]) = v;
    }
    __syncthreads();
#pragma unroll
    for (int it = 0; it < 3; it++) {
        int idx = it * 256 + tid;
        int d = idx >> 3, c = idx & 7;
        int col = j0 + c * 8;
        if (col < 232) {
            short8 v;
#pragma unroll
            for (int k = 0; k < 8; k++) v[k] = T[c * 8 + k][d];
            *(short8*)(Vtg + ((size_t)bh * 96 + d) * 232 + col) = v;
        }
    }
}

// =====================================================================
// Fused attention. Round 6: 2 blocks per (b,h) — block g handles query
// tiles [g*7, g*7+7) / [7,13). Grid 512 = 2 blocks/CU (LDS 2x49.6KB fits),
// halves of a bh are 256 apart so they land on the same XCD (256%8==0)
// and share K/V in L2. Per-wave serial chain halves; co-resident block
// hides the latency phases.
// =====================================================================
__global__ __launch_bounds__(256, 1) void fattn_k(
    const __hip_bfloat16* __restrict__ qkv,
    const __hip_bfloat16* __restrict__ Vtg,
    __hip_bfloat16* __restrict__ atth)
{
    __shared__ __align__(16) char SL[44544 + 4 * 1280];
    char* const Ps = SL + 44544;
    const int tid = threadIdx.x, lane = tid & 63, w = tid >> 6;
    const int bh = blockIdx.x & 255;
    const int g  = blockIdx.x >> 8;          // query-half
    const int tbase  = g * 7;
    const int ntiles = g ? 6 : 7;
    const int b = bh >> 3, h = bh & 7;
    const int frow = lane & 15, quad = lane >> 4;

#pragma unroll
    for (int it = 0; it < 10; it++) {
        int c = it * 256 + tid;
        if (c < 197 * 12) {
            int j = c / 12, cc = c % 12;
            short8 v = *(const short8*)(qkv + ((size_t)(b * 197 + j)) * 2304 + 768 + h * 96 + cc * 8);
            *(short8*)(SL + j * 208 + cc * 16) = v;
        }
    }
    __syncthreads();

    short8 pf[2][7];
#pragma unroll 1
    for (int t = 0; t < 2; t++) {
        const int ml = w + 4 * t;
        if (ml >= ntiles) break;
        const int mt = tbase + ml;
        const int qi = min(mt * 16 + frow, 196);
        const __hip_bfloat16* qrow = qkv + ((size_t)(b * 197 + qi)) * 2304 + h * 96 + quad * 8;
        short8 qf[3];
#pragma unroll
        for (int kc = 0; kc < 3; kc++) qf[kc] = *(const short8*)(qrow + kc * 32);

        f32x4 sacc[13];
#pragma unroll
        for (int nt = 0; nt < 13; nt++) sacc[nt] = (f32x4){0.f, 0.f, 0.f, 0.f};
#pragma unroll
        for (int nt = 0; nt < 13; nt++) {
#pragma unroll
            for (int kc = 0; kc < 3; kc++) {
                short8 kf = *(const short8*)(SL + (nt * 16 + frow) * 208 + (kc * 32 + quad * 8) * 2);
                sacc[nt] = __builtin_amdgcn_mfma_f32_16x16x32_bf16(qf[kc], kf, sacc[nt], 0, 0, 0);
            }
        }

        float mx[4] = {-1e30f, -1e30f, -1e30f, -1e30f};
#pragma unroll
        for (int nt = 0; nt < 13; nt++) {
            bool masked = (nt == 12) && (frow >= 5);
#pragma unroll
            for (int r = 0; r < 4; r++) {
                float v = masked ? -1e30f : sacc[nt][r];
                sacc[nt][r] = v;
                mx[r] = fmaxf(mx[r], v);
            }
        }
#pragma unroll
        for (int m = 1; m <= 8; m <<= 1)
#pragma unroll
            for (int r = 0; r < 4; r++) mx[r] = fmaxf(mx[r], __shfl_xor(mx[r], m));
        float sm[4] = {0.f, 0.f, 0.f, 0.f};
#pragma unroll
        for (int nt = 0; nt < 13; nt++) {
            bool masked = (nt == 12) && (frow >= 5);
#pragma unroll
            for (int r = 0; r < 4; r++) {
                float e = masked ? 0.f : __expf(sacc[nt][r] - mx[r]);
                sacc[nt][r] = e;
                sm[r] += e;
            }
        }
#pragma unroll
        for (int m = 1; m <= 8; m <<= 1)
#pragma unroll
            for (int r = 0; r < 4; r++) sm[r] += __shfl_xor(sm[r], m);
        float inv[4];
#pragma unroll
        for (int r = 0; r < 4; r++) inv[r] = SCALE / sm[r];

        char* const myPs = Ps + w * 1280;
#pragma unroll
        for (int kc = 0; kc < 7; kc++) {
#pragma unroll
            for (int tt = 0; tt < 2; tt++) {
                int t2 = kc * 2 + tt;
#pragma unroll
                for (int r = 0; r < 4; r++) {
                    float pv = (t2 < 13) ? sacc[t2][r] * inv[r] : 0.f;
                    *(__hip_bfloat16*)(myPs + (quad * 4 + r) * 80 + (tt * 16 + frow) * 2) =
                        __float2bfloat16(pv);
                }
            }
            pf[t][kc] = *(const short8*)(myPs + frow * 80 + quad * 16);
        }
    }
    __syncthreads();

    {
        const char* src = (const char*)(Vtg + (size_t)bh * 96 * 232);
#pragma unroll
        for (int i = 0; i < 11; i++) {
            int c = i * 256 + w * 64 + lane;
            if (c < 96 * 29)
                async_cp16(src + (size_t)c * 16, SL + (size_t)(i * 256 + w * 64) * 16);
        }
    }
    __syncthreads();

#pragma unroll 1
    for (int t = 0; t < 2; t++) {
        const int ml = w + 4 * t;
        if (ml >= ntiles) break;
        const int mt = tbase + ml;
        f32x4 oacc[6];
#pragma unroll
        for (int dt = 0; dt < 6; dt++) oacc[dt] = (f32x4){0.f, 0.f, 0.f, 0.f};
#pragma unroll
        for (int kc = 0; kc < 7; kc++) {
#pragma unroll
            for (int dt = 0; dt < 6; dt++) {
                short8 vf = *(const short8*)(SL + (size_t)(dt * 16 + frow) * 464 +
                                             (kc * 32 + quad * 8) * 2);
                oacc[dt] = __builtin_amdgcn_mfma_f32_16x16x32_bf16(pf[t][kc], vf, oacc[dt], 0, 0, 0);
            }
        }
#pragma unroll
        for (int dt = 0; dt < 6; dt++)
#pragma unroll
            for (int r = 0; r < 4; r++) {
                int i = mt * 16 + quad * 4 + r;
                if (i < 197)
                    atth[((size_t)bh * 197 + i) * 96 + dt * 16 + frow] =
                        __float2bfloat16(oacc[dt][r]);
            }
    }
}

// =====================================================================
// x = LN(x + t); writes f32 X in place and bf16 shadow Xb
// =====================================================================
__global__ void add_ln_k(float* __restrict__ X, const float* __restrict__ T,
                         const float* __restrict__ g, const float* __restrict__ bb,
                         __hip_bfloat16* __restrict__ Xb) {
    const size_t row = blockIdx.x;
    float* xr = X + row * E;
    const float* tr = T + row * E;
    const int t = threadIdx.x;
    __shared__ float red[4];
    float v[3];
    float s = 0.f;
#pragma unroll
    for (int i = 0; i < 3; i++) {
        v[i] = xr[t + i * 256] + tr[t + i * 256];
        s += v[i];
    }
    for (int off = 32; off > 0; off >>= 1) s += __shfl_down(s, off);
    int wid = t >> 6, lane = t & 63;
    if (lane == 0) red[wid] = s;
    __syncthreads();
    if (t == 0) red[0] = red[0] + red[1] + red[2] + red[3];
    __syncthreads();
    float mean = red[0] / 768.f;
    __syncthreads();
    float s2 = 0.f;
#pragma unroll
    for (int i = 0; i < 3; i++) {
        float dl = v[i] - mean;
        s2 += dl * dl;
    }
    for (int off = 32; off > 0; off >>= 1) s2 += __shfl_down(s2, off);
    if (lane == 0) red[wid] = s2;
    __syncthreads();
    if (t == 0) red[0] = red[0] + red[1] + red[2] + red[3];
    __syncthreads();
    float rs = rsqrtf(red[0] / 768.f + EPSc);
#pragma unroll
    for (int i = 0; i < 3; i++) {
        int e = t + i * 256;
        float o = (v[i] - mean) * rs * g[e] + bb[e];
        xr[e] = o;
        Xb[row * E + e] = __float2bfloat16(o);
    }
}

// =====================================================================
// pooling, stage 1: partial sums over n-chunks.
// grid (Bsz, 7): block (b,c) sums rows [c*28, ...) for all 768 e.
// =====================================================================
__global__ void pool_part_k(const float* __restrict__ X, float* __restrict__ part) {
    const int b = blockIdx.x, c = blockIdx.y, t = threadIdx.x;
    const int n0 = c * 28;
    const int n1 = (c == 6) ? Nn : n0 + 28;
    float a0 = 0.f, a1 = 0.f, a2 = 0.f;
    for (int n = n0; n < n1; n++) {
        const float* r = X + ((size_t)(b * Nn + n)) * E;
        a0 += r[t];
        a1 += r[t + 256];
        a2 += r[t + 512];
    }
    float* o = part + ((size_t)(b * 7 + c)) * E;
    o[t] = a0;
    o[t + 256] = a1;
    o[t + 512] = a2;
}

// =====================================================================
// pooling, stage 2: combine partials, mean, LN -> pooled
// =====================================================================
__global__ void pool_fin_k(const float* __restrict__ part, const float* __restrict__ g,
                           const float* __restrict__ bb, float* __restrict__ pooled) {
    __shared__ float red[4];
    const int b = blockIdx.x, t = threadIdx.x;
    float loc[3];
#pragma unroll
    for (int i = 0; i < 3; i++) {
        int e = t + i * 256;
        float s = 0.f;
#pragma unroll
        for (int c = 0; c < 7; c++) s += part[((size_t)(b * 7 + c)) * E + e];
        loc[i] = s / (float)Nn;
    }
    float s = loc[0] + loc[1] + loc[2];
    for (int off = 32; off > 0; off >>= 1) s += __shfl_down(s, off);
    int wid = t >> 6, lane = t & 63;
    if (lane == 0) red[wid] = s;
    __syncthreads();
    if (t == 0) red[0] = red[0] + red[1] + red[2] + red[3];
    __syncthreads();
    float mean = red[0] / 768.f;
    __syncthreads();
    float s2 = 0.f;
#pragma unroll
    for (int i = 0; i < 3; i++) {
        float dl = loc[i] - mean;
        s2 += dl * dl;
    }
    for (int off = 32; off > 0; off >>= 1) s2 += __shfl_down(s2, off);
    if (lane == 0) red[wid] = s2;
    __syncthreads();
    if (t == 0) red[0] = red[0] + red[1] + red[2] + red[3];
    __syncthreads();
    float rs = rsqrtf(red[0] / 768.f + EPSc);
#pragma unroll
    for (int i = 0; i < 3; i++) {
        int e = t + i * 256;
        pooled[(size_t)b * E + e] = (loc[i] - mean) * rs * g[e] + bb[e];
    }
}

// =====================================================================
// head matvec
// =====================================================================
__global__ void head_k(const float* __restrict__ pooled, const float* __restrict__ hw,
                       const float* __restrict__ hb, float* __restrict__ out) {
    __shared__ float ps[768];
    const int b = blockIdx.y;
    const int s = blockIdx.x;
    const int t = threadIdx.x, lane = t & 63, w = t >> 6;
    for (int e = t; e < 768; e += 256) ps[e] = pooled[(size_t)b * E + e];
    __syncthreads();
    float pl[12];
#pragma unroll
    for (int j = 0; j < 12; j++) pl[j] = ps[j * 64 + lane];
    for (int i = 0; i < 10; i++) {
        int o = s * 40 + w * 10 + i;
        const float* wr = hw + (size_t)o * 768;
        float acc = 0.f;
#pragma unroll
        for (int j = 0; j < 12; j++) acc += pl[j] * wr[j * 64 + lane];
        for (int off = 32; off > 0; off >>= 1) acc += __shfl_down(acc, off);
        if (lane == 0) out[(size_t)b * NC + o] = acc + hb[o];
    }
}

// =====================================================================
extern "C" void kernel_launch(void* const* d_in, const int* in_sizes, int n_in,
                              void* d_out, int out_size, void* d_ws, size_t ws_size,
                              hipStream_t stream) {
    const float* x        = (const float*)d_in[0];
    const float* conv_w   = (const float*)d_in[1];
    const float* conv_b   = (const float*)d_in[2];
    const float* cls_tok  = (const float*)d_in[3];
    const float* pos_emb  = (const float*)d_in[4];
    const float* qkv_w    = (const float*)d_in[5];
    const float* qkv_b    = (const float*)d_in[6];
    const float* proj_w   = (const float*)d_in[7];
    const float* proj_b   = (const float*)d_in[8];
    const float* ln1_g    = (const float*)d_in[9];
    const float* ln1_b    = (const float*)d_in[10];
    const float* mlp_w1   = (const float*)d_in[11];
    const float* mlp_b1   = (const float*)d_in[12];
    const float* mlp_w2   = (const float*)d_in[13];
    const float* mlp_b2   = (const float*)d_in[14];
    const float* ln2_g    = (const float*)d_in[15];
    const float* ln2_b    = (const float*)d_in[16];
    const float* hln_g    = (const float*)d_in[17];
    const float* hln_b    = (const float*)d_in[18];
    const float* head_w   = (const float*)d_in[19];
    const float* head_b   = (const float*)d_in[20];
    float* out = (float*)d_out;

    const int M = Bsz * Nn;  // 6304

    // ---- workspace carve-up ----
    char* p = (char*)d_ws;
    __hip_bfloat16* Xb   = (__hip_bfloat16*)p;  p += (size_t)M * E * 2;
    float*          X    = (float*)p;           p += (size_t)M * E * 4;
    __hip_bfloat16* qwb  = (__hip_bfloat16*)p;  p += (size_t)3 * E * E * 2;
    __hip_bfloat16* pwb  = (__hip_bfloat16*)p;  p += (size_t)E * E * 2;
    __hip_bfloat16* w1b  = (__hip_bfloat16*)p;  p += (size_t)FF * E * 2;
    __hip_bfloat16* w2b  = (__hip_bfloat16*)p;  p += (size_t)E * FF * 2;
    __hip_bfloat16* cwb  = (__hip_bfloat16*)p;  p += (size_t)E * E * 2;
    __hip_bfloat16* atth = (__hip_bfloat16*)p;  p += (size_t)M * E * 2;  // head-major [bh][197][96]
    float*          pool = (float*)p;           p += (size_t)Bsz * E * 4;
    char* R = p;
    // live set A (attention): qkvb + Vtg ; live set B (patch/MLP): Hb + Ctmp
    __hip_bfloat16* qkvb = (__hip_bfloat16*)R;
    __hip_bfloat16* Vtg  = (__hip_bfloat16*)(R + 29048832);
    __hip_bfloat16* Hb   = (__hip_bfloat16*)R;
    float*          Ctmp = (float*)(R + 40452096);
    __hip_bfloat16* imb  = (__hip_bfloat16*)R;

    // ---- patch embed ----
    {
        f2b_k<<<(E * E / 4 + 255) / 256, 256, 0, stream>>>(conv_w, cwb, E * E / 4);
        int tot = Bsz * NP * 768;
        im2col_k<<<(tot + 255) / 256, 256, 0, stream>>>(x, imb);
        dim3 g(98, 6);  // M=6272 = 98*64
        gemm_bf16_k<64, 0, 0, 0><<<g, 256, 0, stream>>>(imb, cwb, conv_b, Ctmp, Bsz * NP, E, E);
        int tot2 = Bsz * Nn * E;
        assemble_k<<<(tot2 + 255) / 256, 256, 0, stream>>>(Ctmp, cls_tok, pos_emb, X, Xb);
    }

    const int MB128 = (M + 127) / 128;  // 50
    const int MB64  = (M + 63) / 64;    // 99
    const int cn0 = 3 * E * E / 4, cn1 = E * E / 4, cn2 = FF * E / 4, cn3 = E * FF / 4;
    const int cgrid = (cn0 + cn1 + cn2 + cn3 + 255) / 256;

    // ---- transformer layers ----
    for (int l = 0; l < Lnum; l++) {
        const float* qw = qkv_w + (size_t)l * 3 * E * E;
        const float* qb = qkv_b + (size_t)l * 3 * E;
        const float* pw = proj_w + (size_t)l * E * E;
        const float* pb = proj_b + (size_t)l * E;
        const float* g1 = ln1_g + (size_t)l * E;
        const float* b1 = ln1_b + (size_t)l * E;
        const float* w1 = mlp_w1 + (size_t)l * FF * E;
        const float* bb1 = mlp_b1 + (size_t)l * FF;
        const float* w2 = mlp_w2 + (size_t)l * E * FF;
        const float* bb2 = mlp_b2 + (size_t)l * E;
        const float* g2 = ln2_g + (size_t)l * E;
        const float* b2 = ln2_b + (size_t)l * E;

        f2b4_k<<<cgrid, 256, 0, stream>>>(qw, pw, w1, w2, qwb, pwb, w1b, w2b,
                                          cn0, cn1, cn2, cn3);

        // qkv = Xb @ qwb^T -> bf16 [M, 2304]
        gemm_bf16_k<128, 1, 0, 0><<<dim3(MB128, 18), 256, 0, stream>>>(Xb, qwb, qb, qkvb, M, 3 * E, E);
        // V transpose into Vtg
        vtr_k<<<dim3(4, Bsz * HEADS), 256, 0, stream>>>(qkvb, Vtg);
        // fused attention -> atth (head-major); 2 blocks per (b,h)
        fattn_k<<<Bsz * HEADS * 2, 256, 0, stream>>>(qkvb, Vtg, atth);
        // proj (A head-major) -> f32 Ctmp
        gemm_bf16_k<64, 0, 0, 1><<<dim3(MB64, 6), 256, 0, stream>>>(atth, pwb, pb, Ctmp, M, E, E);
        add_ln_k<<<M, 256, 0, stream>>>(X, Ctmp, g1, b1, Xb);
        // MLP1 + gelu -> bf16 Hb
        gemm_bf16_k<128, 1, 1, 0><<<dim3(MB128, 24), 256, 0, stream>>>(Xb, w1b, bb1, Hb, M, FF, E);
        // MLP2 -> f32 Ctmp
        gemm_bf16_k<64, 0, 0, 0><<<dim3(MB64, 6), 256, 0, stream>>>(Hb, w2b, bb2, Ctmp, M, E, FF);
        add_ln_k<<<M, 256, 0, stream>>>(X, Ctmp, g2, b2, Xb);
    }

    // ---- head ----
    pool_part_k<<<dim3(Bsz, 7), 256, 0, stream>>>(X, Ctmp);
    pool_fin_k<<<Bsz, 256, 0, stream>>>(Ctmp, hln_g, hln_b, pool);
    head_k<<<dim3(25, Bsz), 256, 0, stream>>>(pool, head_w, head_b, out);
}